// Round 7
// baseline (616.417 us; speedup 1.0000x reference)
//
#include <hip/hip_runtime.h>
#include <math.h>

// Problem: B=8, C=256, H=25, W=512   (N = B*C*H*W = 26,214,400 elements)
// ws layout (float-slot offsets; bf16 arrays use 2 elements per slot):
//   Xbf   @ 0          (26,214,400 ushort = 13,107,200 slots) scnn1 out, bf16
//   Ybf   @ 13107200   (26,214,400 ushort = 13,107,200 slots) scnn2 out, bf16
//   Mbf   @ 26214400   (65,536 ushort = 32,768 slots)  M row-major bf16
//   coef1 @ 26247168   (512)    bn1 affine a[c], b[c]
//   coef2 @ 26247680   (512)    bn2 affine
//   wh    @ 26248192   (19,200) folded conv/h-reduce weights [c][hh][kw]
//   --- zeroed zone (one memset: 13,312 floats) ---
//   T     @ 26267392   (12,288) T[kw][b][v]
//   st1   @ 26279680   (512)    scnn1 sums/sumsq
//   st2   @ 26280192   (512)    scnn2 sums/sumsq
//   --- end zero zone ---
//   r     @ 26280704   (8,192)  reduced map (8 x 1024), fully overwritten
// total = 26,288,896 floats = 105,155,584 bytes of d_ws.

#define XBF_OFF    0
#define YBF_OFF    13107200
#define MBF_OFF    26214400
#define COEF1_OFF  26247168
#define COEF2_OFF  26247680
#define WH_OFF     26248192
#define T_OFF      26267392
#define ST1_OFF    26279680
#define ST2_OFF    26280192
#define R_OFF      26280704
#define ZERO_FLOATS 13312

typedef __attribute__((ext_vector_type(8))) short bf16x8;  // MFMA A/B frag
typedef __attribute__((ext_vector_type(4))) float f32x4;   // MFMA C/D frag

__device__ __forceinline__ ushort f2bf(float f) {          // RNE f32 -> bf16 bits
    uint32_t b = __float_as_uint(f);
    b += 0x7fffu + ((b >> 16) & 1u);
    return (ushort)(b >> 16);
}
__device__ __forceinline__ float bf2f(ushort u) {
    return __uint_as_float((uint32_t)u << 16);
}

__global__ __launch_bounds__(256) void prep_mbf(const float* __restrict__ wmsg,
                                                ushort* __restrict__ Mbf)
{
    int idx = blockIdx.x * 256 + threadIdx.x;   // o*256 + i
    Mbf[idx] = f2bf(wmsg[(size_t)idx * 9 + 4]); // w_msg[o,i,4,0]
}

// wh[c][hh][kw] = sum_kh(valid) w2[hh-kh+1] * (sum_o w1[o]*w_up2[o,c,kh,kw])
__global__ __launch_bounds__(256) void prep_wh(const float* __restrict__ wup2,
                                               const float* __restrict__ w1,
                                               const float* __restrict__ w2,
                                               float* __restrict__ wh)
{
    const int c  = blockIdx.x / 3;
    const int kw = blockIdx.x % 3;
    const int o  = threadIdx.x;
    const float w1o = w1[o];
    __shared__ float red[3][256];
    red[0][o] = w1o * wup2[(size_t)((o * 256 + c) * 3 + 0) * 3 + kw];
    red[1][o] = w1o * wup2[(size_t)((o * 256 + c) * 3 + 1) * 3 + kw];
    red[2][o] = w1o * wup2[(size_t)((o * 256 + c) * 3 + 2) * 3 + kw];
    __syncthreads();
    for (int st = 128; st > 0; st >>= 1) {
        if (o < st) {
            red[0][o] += red[0][o + st];
            red[1][o] += red[1][o + st];
            red[2][o] += red[2][o + st];
        }
        __syncthreads();
    }
    if (o < 25) {
        float s = 0.f;
        #pragma unroll
        for (int kh = 0; kh < 3; ++kh) {
            int m = o - kh + 1;
            if (m >= 0 && m < 25) s = fmaf(w2[m], red[kh][0], s);
        }
        wh[(c * 25 + o) * 3 + kw] = s;
    }
}

// ---------------- MFMA scan, register-resident x ----------------
// Block = 16 (b,w) columns, 512 threads = 8 waves; wave wid owns o-tiles
// {2wid, 2wid+1}. A = M bf16 register-resident. ALL 25 steps of x preloaded
// into 100 VGPRs (bf16-packed) in one coalesced burst -> the 25-step loop has
// ZERO global loads and no vmcnt waits (stores are fire-and-forget). State
// in LDS in B-FRAGMENT ORDER, XOR-swizzled (bit5 ^= bit8); one raw s_barrier
// + lgkmcnt(0) per step. Loop fully unrolled (xreg indices compile-time).
// out row h gets s_{24-h} (reversed order), bf16.
// coef != null: input v -> relu(a[o]*v + b[o]).
template <bool INBF>
__global__ __launch_bounds__(512, 2) void scnn_mfma(const void* __restrict__ xin_,
                                                    const ushort* __restrict__ Mbf,
                                                    ushort* __restrict__ outb,
                                                    const float* __restrict__ coef,
                                                    float* __restrict__ stats)
{
    __shared__ ulong2 lds_[1024];          // 16 KB: 2 x 8 KB state buffers
    char* lds = (char*)lds_;
    const float*  xf = (const float*)xin_;
    const ushort* xh = (const ushort*)xin_;

    const int tid   = threadIdx.x;
    const int lane  = tid & 63;
    const int wid   = tid >> 6;        // 0..7
    const int row16 = lane & 15;       // B-col == D-col == column index
    const int g     = lane >> 4;       // 0..3
    const int b     = blockIdx.x >> 5;
    const int w0    = (blockIdx.x & 31) << 4;
    const int to0   = wid * 2;

    // LDS read base (per-lane, swizzled); chunk kk at +kk*1024
    const int lofs = (lane * 16) ^ (((lane >> 4) & 1) << 5);
    // LDS write offsets: target reader-lane L=(tt*2+(g>>1))*16+row16, byte (g&1)*8
    int woff[2];
    #pragma unroll
    for (int tt = 0; tt < 2; ++tt) {
        int inner = (tt * 2 + (g >> 1)) * 256 + row16 * 16 + (g & 1) * 8;
        woff[tt] = wid * 1024 + (inner ^ (((inner >> 8) & 1) << 5));
    }

    // A fragments: lane holds M[(to*16+row16)][kk*32 + g*8 .. +7]
    bf16x8 afrag[2][8];
    #pragma unroll
    for (int tt = 0; tt < 2; ++tt) {
        const ushort* mrow = Mbf + (size_t)((to0 + tt) * 16 + row16) * 256 + g * 8;
        #pragma unroll
        for (int kk = 0; kk < 8; ++kk)
            afrag[tt][kk] = *reinterpret_cast<const bf16x8*>(mrow + kk * 32);
    }

    const bool hasbn = (coef != nullptr);
    float ca[2][4], cb[2][4];
    if (hasbn) {
        #pragma unroll
        for (int tt = 0; tt < 2; ++tt)
            #pragma unroll
            for (int r = 0; r < 4; ++r) {
                int o = (to0 + tt) * 16 + g * 4 + r;
                ca[tt][r] = coef[o];
                cb[tt][r] = coef[256 + o];
            }
    }

    // 32-bit element offsets (max 26.2M < 2^32)
    uint ofs[2][4];
    #pragma unroll
    for (int tt = 0; tt < 2; ++tt)
        #pragma unroll
        for (int r = 0; r < 4; ++r) {
            int o = (to0 + tt) * 16 + g * 4 + r;
            ofs[tt][r] = (uint)((b * 256 + o) * 12800 + w0 + row16);
        }

    // ---- preload all 25 steps of x, bf16-packed: xreg[t*4 + tt*2 + rq] ----
    uint xreg[100];
    #pragma unroll
    for (int t = 0; t < 25; ++t)
        #pragma unroll
        for (int tt = 0; tt < 2; ++tt)
            #pragma unroll
            for (int rq = 0; rq < 2; ++rq) {
                uint a0 = ofs[tt][2 * rq]     + (uint)t * 512u;
                uint a1 = ofs[tt][2 * rq + 1] + (uint)t * 512u;
                ushort lo = INBF ? xh[a0] : f2bf(xf[a0]);
                ushort hi = INBF ? xh[a1] : f2bf(xf[a1]);
                xreg[t * 4 + tt * 2 + rq] = (uint)lo | ((uint)hi << 16);
            }

    float s1[2][4] = {{0,0,0,0},{0,0,0,0}};
    float sq[2][4] = {{0,0,0,0},{0,0,0,0}};

    #pragma unroll
    for (int t = 0; t < 25; ++t) {
        f32x4 acc[2] = {{0.f,0.f,0.f,0.f},{0.f,0.f,0.f,0.f}};
        if (t > 0) {                              // compile-time pruned at t=0
            const char* pb = lds + (t & 1) * 8192 + lofs;
            #pragma unroll
            for (int kk = 0; kk < 8; ++kk) {
                bf16x8 bfr = *reinterpret_cast<const bf16x8*>(pb + kk * 1024);
                acc[0] = __builtin_amdgcn_mfma_f32_16x16x32_bf16(afrag[0][kk], bfr, acc[0], 0, 0, 0);
                acc[1] = __builtin_amdgcn_mfma_f32_16x16x32_bf16(afrag[1][kk], bfr, acc[1], 0, 0, 0);
            }
        }

        char* wb = lds + ((t & 1) ^ 1) * 8192;
        #pragma unroll
        for (int tt = 0; tt < 2; ++tt) {
            ushort us[4];
            #pragma unroll
            for (int r = 0; r < 4; ++r) {
                float x = bf2f((ushort)(xreg[t * 4 + tt * 2 + (r >> 1)] >> ((r & 1) * 16)));
                if (hasbn) x = fmaxf(fmaf(ca[tt][r], x, cb[tt][r]), 0.0f);
                float cv = x + fmaxf(acc[tt][r], 0.0f);
                us[r] = f2bf(cv);
                outb[ofs[tt][r] + (uint)(24 - t) * 512u] = us[r];  // reversed row
                s1[tt][r] += cv;
                sq[tt][r] = fmaf(cv, cv, sq[tt][r]);
            }
            *reinterpret_cast<ushort4*>(wb + woff[tt]) =
                make_ushort4(us[0], us[1], us[2], us[3]);
        }

        if (t < 24) {
            // LDS-only barrier: order ds_write -> barrier; vmcnt NOT touched.
            asm volatile("s_waitcnt lgkmcnt(0)" ::: "memory");
            __builtin_amdgcn_s_barrier();
            __builtin_amdgcn_sched_barrier(0);
        }
    }

    // fused per-channel stats: reduce across the 16 lanes sharing one o
    #pragma unroll
    for (int tt = 0; tt < 2; ++tt)
        #pragma unroll
        for (int r = 0; r < 4; ++r) {
            float a = s1[tt][r], q = sq[tt][r];
            #pragma unroll
            for (int m = 8; m >= 1; m >>= 1) {
                a += __shfl_xor(a, m, 64);
                q += __shfl_xor(q, m, 64);
            }
            if (row16 == 0) {
                int o = (to0 + tt) * 16 + g * 4 + r;
                atomicAdd(&stats[o], a);
                atomicAdd(&stats[256 + o], q);
            }
        }
}

__global__ __launch_bounds__(256) void coef_kernel(const float* __restrict__ stats,
                                                   const float* __restrict__ gamma,
                                                   const float* __restrict__ beta,
                                                   float* __restrict__ coef)
{
    int c = threadIdx.x;
    float mean = stats[c] * (1.0f / 102400.0f);
    float var  = stats[256 + c] * (1.0f / 102400.0f) - mean * mean;
    float a = gamma[c] * rsqrtf(var + 1e-5f);
    coef[c] = a;
    coef[256 + c] = beta[c] - mean * a;
}

// T[kw][b][v] = sum_{c,hh} wh[c,hh,kw] * relu(bn2(Y[b,c,hh,v])), Y in bf16.
// Block = (b, 8-channel chunk); 256 threads, 2 v each (uint = bf16x2 loads).
__global__ __launch_bounds__(256) void conv_reduce(const ushort* __restrict__ Y,
                                                   const float* __restrict__ coef2,
                                                   const float* __restrict__ wh,
                                                   float* __restrict__ T)
{
    const int v2 = threadIdx.x;            // v = 2*v2, 2*v2+1
    const int b  = blockIdx.x >> 5;
    const int c0 = (blockIdx.x & 31) << 3;

    __shared__ float whL[8][25][3];
    for (int i = threadIdx.x; i < 600; i += 256) {
        int ci = i / 75, rem = i % 75;
        whL[ci][rem / 3][rem % 3] = wh[(c0 + ci) * 75 + rem];
    }
    __syncthreads();

    float a0[2] = {0,0}, a1[2] = {0,0}, a2[2] = {0,0};
    for (int ci = 0; ci < 8; ++ci) {
        int c = c0 + ci;
        float sa = coef2[c], bo = coef2[256 + c];
        const uint* rowb = (const uint*)(Y + (size_t)(b * 256 + c) * 12800) + v2;
        #pragma unroll 5
        for (int hh = 0; hh < 25; ++hh) {
            uint yy = rowb[hh * 256];
            float z0 = fmaxf(fmaf(sa, bf2f((ushort)(yy & 0xffffu)), bo), 0.f);
            float z1 = fmaxf(fmaf(sa, bf2f((ushort)(yy >> 16)),     bo), 0.f);
            float wc0 = whL[ci][hh][0], wc1 = whL[ci][hh][1], wc2 = whL[ci][hh][2];
            a0[0] = fmaf(wc0, z0, a0[0]); a0[1] = fmaf(wc0, z1, a0[1]);
            a1[0] = fmaf(wc1, z0, a1[0]); a1[1] = fmaf(wc1, z1, a1[1]);
            a2[0] = fmaf(wc2, z0, a2[0]); a2[1] = fmaf(wc2, z1, a2[1]);
        }
    }
    const int vb = 2 * v2;
    atomicAdd(&T[(0 * 8 + b) * 512 + vb],     a0[0]);
    atomicAdd(&T[(0 * 8 + b) * 512 + vb + 1], a0[1]);
    atomicAdd(&T[(1 * 8 + b) * 512 + vb],     a1[0]);
    atomicAdd(&T[(1 * 8 + b) * 512 + vb + 1], a1[1]);
    atomicAdd(&T[(2 * 8 + b) * 512 + vb],     a2[0]);
    atomicAdd(&T[(2 * 8 + b) * 512 + vb + 1], a2[1]);
}

// r[b,w'] = sum_kw (valid u=w'+kw-1) interp_512->1024(T[kw][b])[u]
__global__ __launch_bounds__(256) void combine_r(const float* __restrict__ T,
                                                 float* __restrict__ r)
{
    int idx = blockIdx.x * 256 + threadIdx.x;   // 8192
    int b = idx >> 10, w = idx & 1023;
    const float scale = (float)(511.0 / 1023.0);
    float acc = 0.f;
    #pragma unroll
    for (int kw = 0; kw < 3; ++kw) {
        int u = w + kw - 1;
        if (u >= 0 && u < 1024) {
            float pos = (float)u * scale;
            int i0 = (int)pos;
            float f = pos - (float)i0;
            int i1 = min(i0 + 1, 511);
            const float* Tk = T + (size_t)(kw * 8 + b) * 512;
            float lo = Tk[i0];
            acc += fmaf(Tk[i1] - lo, f, lo);
        }
    }
    r[idx] = acc;
}

// out[b,w4] = sigmoid( up_{2048->4096}( up_{1024->2048}(r) ) )
__global__ __launch_bounds__(256) void final_kernel(const float* __restrict__ r,
                                                    float* __restrict__ out)
{
    int idx = blockIdx.x * 256 + threadIdx.x;   // 32768
    int b = idx >> 12, w4 = idx & 4095;
    const float s3 = (float)(2047.0 / 4095.0);
    const float s2 = (float)(1023.0 / 2047.0);
    const float* rb = r + b * 1024;

    float pos3 = (float)w4 * s3;
    int j0 = (int)pos3;
    float f3 = pos3 - (float)j0;
    int j1 = min(j0 + 1, 2047);

    float v[2];
    int jj[2] = {j0, j1};
    #pragma unroll
    for (int k = 0; k < 2; ++k) {
        float p = (float)jj[k] * s2;
        int i = (int)p;
        float f = p - (float)i;
        int i2 = min(i + 1, 1023);
        float lo = rb[i];
        v[k] = fmaf(rb[i2] - lo, f, lo);
    }
    float z = fmaf(v[1] - v[0], f3, v[0]);
    out[idx] = 1.0f / (1.0f + expf(-z));
}

extern "C" void kernel_launch(void* const* d_in, const int* in_sizes, int n_in,
                              void* d_out, int out_size, void* d_ws, size_t ws_size,
                              hipStream_t stream)
{
    const float* p2c   = (const float*)d_in[0];
    const float* wmsg  = (const float*)d_in[1];
    const float* gamma = (const float*)d_in[2];
    const float* beta  = (const float*)d_in[3];
    const float* wup2  = (const float*)d_in[4];
    const float* wc1   = (const float*)d_in[5];
    const float* wc2   = (const float*)d_in[6];
    float* out = (float*)d_out;
    float* ws  = (float*)d_ws;

    ushort* Xbf   = (ushort*)(ws + XBF_OFF);
    ushort* Ybf   = (ushort*)(ws + YBF_OFF);
    ushort* Mbf   = (ushort*)(ws + MBF_OFF);
    float*  coef1 = ws + COEF1_OFF;
    float*  coef2 = ws + COEF2_OFF;
    float*  wh    = ws + WH_OFF;
    float*  T     = ws + T_OFF;
    float*  st1   = ws + ST1_OFF;
    float*  st2   = ws + ST2_OFF;
    float*  r     = ws + R_OFF;

    hipMemsetAsync(T, 0, ZERO_FLOATS * sizeof(float), stream);  // T, st1, st2

    prep_mbf<<<256, 256, 0, stream>>>(wmsg, Mbf);
    prep_wh<<<768, 256, 0, stream>>>(wup2, wc1, wc2, wh);

    // scnn1: f32 input -> Xbf (bf16, logical order) + stats
    scnn_mfma<false><<<256, 512, 0, stream>>>(p2c, Mbf, Xbf, nullptr, st1);
    coef_kernel<<<1, 256, 0, stream>>>(st1, gamma, beta, coef1);

    // scnn2: reads relu(bn1(Xbf)) -> Ybf + stats
    scnn_mfma<true><<<256, 512, 0, stream>>>(Xbf, Mbf, Ybf, coef1, st2);
    coef_kernel<<<1, 256, 0, stream>>>(st2, gamma, beta, coef2);

    // folded conv + h-reduction, decomposed through the linear upsample
    conv_reduce<<<256, 256, 0, stream>>>(Ybf, coef2, wh, T);
    combine_r<<<32, 256, 0, stream>>>(T, r);

    // two upsamples + sigmoid
    final_kernel<<<128, 256, 0, stream>>>(r, out);
}

// Round 8
// 275.802 us; speedup vs baseline: 2.2350x; 2.2350x over previous
//
#include <hip/hip_runtime.h>
#include <math.h>

// Problem: B=8, C=256, H=25, W=512   (N = B*C*H*W = 26,214,400 elements)
// ws layout (float-slot offsets; bf16 arrays use 2 elements per slot):
//   Xbf   @ 0          (26,214,400 ushort = 13,107,200 slots) scnn1 out, bf16
//   Ybf   @ 13107200   (26,214,400 ushort = 13,107,200 slots) scnn2 out, bf16
//   Mbf   @ 26214400   (65,536 ushort = 32,768 slots)  M row-major bf16
//   coef1 @ 26247168   (512)    bn1 affine a[c], b[c]
//   coef2 @ 26247680   (512)    bn2 affine
//   wh    @ 26248192   (19,200) folded conv/h-reduce weights [c][hh][kw]
//   --- zeroed zone (one memset: 13,312 floats) ---
//   T     @ 26267392   (12,288) T[kw][b][v]
//   st1   @ 26279680   (512)    scnn1 sums/sumsq
//   st2   @ 26280192   (512)    scnn2 sums/sumsq
//   --- end zero zone ---
//   r     @ 26280704   (8,192)  reduced map (8 x 1024), fully overwritten
// total = 26,288,896 floats = 105,155,584 bytes of d_ws.

#define XBF_OFF    0
#define YBF_OFF    13107200
#define MBF_OFF    26214400
#define COEF1_OFF  26247168
#define COEF2_OFF  26247680
#define WH_OFF     26248192
#define T_OFF      26267392
#define ST1_OFF    26279680
#define ST2_OFF    26280192
#define R_OFF      26280704
#define ZERO_FLOATS 13312

typedef __attribute__((ext_vector_type(8))) short bf16x8;  // MFMA A/B frag
typedef __attribute__((ext_vector_type(4))) float f32x4;   // MFMA C/D frag

__device__ __forceinline__ ushort f2bf(float f) {          // RNE f32 -> bf16 bits
    uint32_t b = __float_as_uint(f);
    b += 0x7fffu + ((b >> 16) & 1u);
    return (ushort)(b >> 16);
}
__device__ __forceinline__ float bf2f(ushort u) {
    return __uint_as_float((uint32_t)u << 16);
}

__global__ __launch_bounds__(256) void prep_mbf(const float* __restrict__ wmsg,
                                                ushort* __restrict__ Mbf)
{
    int idx = blockIdx.x * 256 + threadIdx.x;   // o*256 + i
    Mbf[idx] = f2bf(wmsg[(size_t)idx * 9 + 4]); // w_msg[o,i,4,0]
}

// wh[c][hh][kw] = sum_kh(valid) w2[hh-kh+1] * (sum_o w1[o]*w_up2[o,c,kh,kw])
__global__ __launch_bounds__(256) void prep_wh(const float* __restrict__ wup2,
                                               const float* __restrict__ w1,
                                               const float* __restrict__ w2,
                                               float* __restrict__ wh)
{
    const int c  = blockIdx.x / 3;
    const int kw = blockIdx.x % 3;
    const int o  = threadIdx.x;
    const float w1o = w1[o];
    __shared__ float red[3][256];
    red[0][o] = w1o * wup2[(size_t)((o * 256 + c) * 3 + 0) * 3 + kw];
    red[1][o] = w1o * wup2[(size_t)((o * 256 + c) * 3 + 1) * 3 + kw];
    red[2][o] = w1o * wup2[(size_t)((o * 256 + c) * 3 + 2) * 3 + kw];
    __syncthreads();
    for (int st = 128; st > 0; st >>= 1) {
        if (o < st) {
            red[0][o] += red[0][o + st];
            red[1][o] += red[1][o + st];
            red[2][o] += red[2][o + st];
        }
        __syncthreads();
    }
    if (o < 25) {
        float s = 0.f;
        #pragma unroll
        for (int kh = 0; kh < 3; ++kh) {
            int m = o - kh + 1;
            if (m >= 0 && m < 25) s = fmaf(w2[m], red[kh][0], s);
        }
        wh[(c * 25 + o) * 3 + kw] = s;
    }
}

// ---------------- MFMA scan, x staged through LDS ----------------
// Block = 16 (b,w) columns, 512 threads = 8 waves; wave wid owns o-tiles
// {2wid, 2wid+1}. A = M bf16 register-resident. x is staged into LDS in
// 5-step chunks (bf16, double-buffered, 80 KB) via bulk coalesced loads;
// the 25-step loop reads x ONLY from LDS -> no vmcnt dependency in-loop
// (output stores are fire-and-forget; the one staging vmcnt-wait per chunk
// targets loads OLDER than all intervening stores = non-blocking).
// State in LDS in B-FRAGMENT ORDER, XOR-swizzled (bit5 ^= bit8); one raw
// s_barrier + lgkmcnt(0) per step. Fully unrolled.
// out row h gets s_{24-h} (reversed order), bf16.
// coef != null: input v -> relu(a[o]*v + b[o]).
template <bool INBF>
__global__ __launch_bounds__(512, 2) void scnn_mfma(const void* __restrict__ xin_,
                                                    const ushort* __restrict__ Mbf,
                                                    ushort* __restrict__ outb,
                                                    const float* __restrict__ coef,
                                                    float* __restrict__ stats)
{
    __shared__ ushort xstage[2][20480];    // 2 x 40 KB: [tl][ch][col] per chunk
    __shared__ ulong2 state_[1024];        // 16 KB: 2 x 8 KB state buffers
    char* lds = (char*)state_;
    const float*  xf = (const float*)xin_;
    const ushort* xh = (const ushort*)xin_;

    const int tid   = threadIdx.x;
    const int lane  = tid & 63;
    const int wid   = tid >> 6;        // 0..7
    const int row16 = lane & 15;       // B-col == D-col == column index
    const int g     = lane >> 4;       // 0..3
    const int b     = blockIdx.x >> 5;
    const int w0    = (blockIdx.x & 31) << 4;
    const int to0   = wid * 2;

    // LDS state read base (per-lane, swizzled); chunk kk at +kk*1024
    const int lofs = (lane * 16) ^ (((lane >> 4) & 1) << 5);
    // LDS state write offsets
    int woff[2];
    #pragma unroll
    for (int tt = 0; tt < 2; ++tt) {
        int inner = (tt * 2 + (g >> 1)) * 256 + row16 * 16 + (g & 1) * 8;
        woff[tt] = wid * 1024 + (inner ^ (((inner >> 8) & 1) << 5));
    }

    // A fragments: lane holds M[(to*16+row16)][kk*32 + g*8 .. +7]
    bf16x8 afrag[2][8];
    #pragma unroll
    for (int tt = 0; tt < 2; ++tt) {
        const ushort* mrow = Mbf + (size_t)((to0 + tt) * 16 + row16) * 256 + g * 8;
        #pragma unroll
        for (int kk = 0; kk < 8; ++kk)
            afrag[tt][kk] = *reinterpret_cast<const bf16x8*>(mrow + kk * 32);
    }

    const bool hasbn = (coef != nullptr);
    float ca[2][4], cb[2][4];
    if (hasbn) {
        #pragma unroll
        for (int tt = 0; tt < 2; ++tt)
            #pragma unroll
            for (int r = 0; r < 4; ++r) {
                int o = (to0 + tt) * 16 + g * 4 + r;
                ca[tt][r] = coef[o];
                cb[tt][r] = coef[256 + o];
            }
    }

    // 32-bit element offsets for output stores
    uint ofs[2][4];
    #pragma unroll
    for (int tt = 0; tt < 2; ++tt)
        #pragma unroll
        for (int r = 0; r < 4; ++r) {
            int o = (to0 + tt) * 16 + g * 4 + r;
            ofs[tt][r] = (uint)((b * 256 + o) * 12800 + w0 + row16);
        }

    // ---- x staging: chunk q = steps 5q..5q+4; tuple j*512+tid ----
    // grp = tuple&3 (4 cols), row = tuple>>2, ch = row&255, tl = row>>8
    const uint xbase = (uint)(b * 256) * 12800u + (uint)w0;
    float4  sf[10];
    ushort4 sh[10];

    #define STAGE_LOAD(q)                                                      \
        { _Pragma("unroll") for (int j = 0; j < 10; ++j) {                     \
            uint tup = (uint)(j * 512 + tid);                                  \
            uint grp = tup & 3u, row = tup >> 2;                               \
            uint ch = row & 255u, tl = row >> 8;                               \
            uint e = xbase + ch * 12800u + ((uint)(q) * 5u + tl) * 512u + grp * 4u; \
            if (INBF) sh[j] = *reinterpret_cast<const ushort4*>(xh + e);       \
            else      sf[j] = *reinterpret_cast<const float4*>(xf + e);        \
        } }

    #define STAGE_WRITE(buf)                                                   \
        { _Pragma("unroll") for (int j = 0; j < 10; ++j) {                     \
            uint tup = (uint)(j * 512 + tid);                                  \
            uint grp = tup & 3u, row = tup >> 2;                               \
            uint ch = row & 255u, tl = row >> 8;                               \
            uint idx = (tl * 256u + ch) * 16u + grp * 4u;                      \
            ushort4 v;                                                         \
            if (INBF) v = sh[j];                                               \
            else v = make_ushort4(f2bf(sf[j].x), f2bf(sf[j].y),                \
                                  f2bf(sf[j].z), f2bf(sf[j].w));               \
            *reinterpret_cast<ushort4*>(&xstage[buf][idx]) = v;                \
        } }

    // prologue: fill chunk 0
    STAGE_LOAD(0);
    STAGE_WRITE(0);
    asm volatile("s_waitcnt lgkmcnt(0)" ::: "memory");
    __builtin_amdgcn_s_barrier();
    __builtin_amdgcn_sched_barrier(0);

    float s1[2][4] = {{0,0,0,0},{0,0,0,0}};
    float sq[2][4] = {{0,0,0,0},{0,0,0,0}};

    #pragma unroll
    for (int q = 0; q < 5; ++q) {
        if (q < 4) STAGE_LOAD(q + 1);      // issue early; lands at s==2
        #pragma unroll
        for (int s = 0; s < 5; ++s) {
            const int t = q * 5 + s;

            // x for this step from LDS (lgkm only)
            ushort xu[2][4];
            #pragma unroll
            for (int tt = 0; tt < 2; ++tt)
                #pragma unroll
                for (int r = 0; r < 4; ++r) {
                    int ch = (to0 + tt) * 16 + g * 4 + r;
                    xu[tt][r] = xstage[q & 1][(s * 256 + ch) * 16 + row16];
                }

            f32x4 acc[2] = {{0.f,0.f,0.f,0.f},{0.f,0.f,0.f,0.f}};
            if (t > 0) {                   // compile-time pruned at t=0
                const char* pb = lds + (t & 1) * 8192 + lofs;
                #pragma unroll
                for (int kk = 0; kk < 8; ++kk) {
                    bf16x8 bfr = *reinterpret_cast<const bf16x8*>(pb + kk * 1024);
                    acc[0] = __builtin_amdgcn_mfma_f32_16x16x32_bf16(afrag[0][kk], bfr, acc[0], 0, 0, 0);
                    acc[1] = __builtin_amdgcn_mfma_f32_16x16x32_bf16(afrag[1][kk], bfr, acc[1], 0, 0, 0);
                }
            }

            char* wb = lds + ((t & 1) ^ 1) * 8192;
            #pragma unroll
            for (int tt = 0; tt < 2; ++tt) {
                ushort us[4];
                #pragma unroll
                for (int r = 0; r < 4; ++r) {
                    float x = bf2f(xu[tt][r]);
                    if (hasbn) x = fmaxf(fmaf(ca[tt][r], x, cb[tt][r]), 0.0f);
                    float cv = x + fmaxf(acc[tt][r], 0.0f);
                    us[r] = f2bf(cv);
                    outb[ofs[tt][r] + (uint)(24 - t) * 512u] = us[r];
                    s1[tt][r] += cv;
                    sq[tt][r] = fmaf(cv, cv, sq[tt][r]);
                }
                *reinterpret_cast<ushort4*>(wb + woff[tt]) =
                    make_ushort4(us[0], us[1], us[2], us[3]);
            }

            if (s == 2 && q < 4) STAGE_WRITE((q & 1) ^ 1);

            if (t < 24) {
                // LDS-only barrier: vmcnt NOT drained.
                asm volatile("s_waitcnt lgkmcnt(0)" ::: "memory");
                __builtin_amdgcn_s_barrier();
                __builtin_amdgcn_sched_barrier(0);
            }
        }
    }

    // fused per-channel stats: reduce across the 16 lanes sharing one o
    #pragma unroll
    for (int tt = 0; tt < 2; ++tt)
        #pragma unroll
        for (int r = 0; r < 4; ++r) {
            float a = s1[tt][r], q2 = sq[tt][r];
            #pragma unroll
            for (int m = 8; m >= 1; m >>= 1) {
                a  += __shfl_xor(a, m, 64);
                q2 += __shfl_xor(q2, m, 64);
            }
            if (row16 == 0) {
                int o = (to0 + tt) * 16 + g * 4 + r;
                atomicAdd(&stats[o], a);
                atomicAdd(&stats[256 + o], q2);
            }
        }
}

__global__ __launch_bounds__(256) void coef_kernel(const float* __restrict__ stats,
                                                   const float* __restrict__ gamma,
                                                   const float* __restrict__ beta,
                                                   float* __restrict__ coef)
{
    int c = threadIdx.x;
    float mean = stats[c] * (1.0f / 102400.0f);
    float var  = stats[256 + c] * (1.0f / 102400.0f) - mean * mean;
    float a = gamma[c] * rsqrtf(var + 1e-5f);
    coef[c] = a;
    coef[256 + c] = beta[c] - mean * a;
}

// T[kw][b][v] = sum_{c,hh} wh[c,hh,kw] * relu(bn2(Y[b,c,hh,v])), Y in bf16.
// Block = (b, 8-channel chunk); 256 threads, 2 v each (uint = bf16x2 loads).
__global__ __launch_bounds__(256) void conv_reduce(const ushort* __restrict__ Y,
                                                   const float* __restrict__ coef2,
                                                   const float* __restrict__ wh,
                                                   float* __restrict__ T)
{
    const int v2 = threadIdx.x;            // v = 2*v2, 2*v2+1
    const int b  = blockIdx.x >> 5;
    const int c0 = (blockIdx.x & 31) << 3;

    __shared__ float whL[8][25][3];
    for (int i = threadIdx.x; i < 600; i += 256) {
        int ci = i / 75, rem = i % 75;
        whL[ci][rem / 3][rem % 3] = wh[(c0 + ci) * 75 + rem];
    }
    __syncthreads();

    float a0[2] = {0,0}, a1[2] = {0,0}, a2[2] = {0,0};
    for (int ci = 0; ci < 8; ++ci) {
        int c = c0 + ci;
        float sa = coef2[c], bo = coef2[256 + c];
        const uint* rowb = (const uint*)(Y + (size_t)(b * 256 + c) * 12800) + v2;
        #pragma unroll 5
        for (int hh = 0; hh < 25; ++hh) {
            uint yy = rowb[hh * 256];
            float z0 = fmaxf(fmaf(sa, bf2f((ushort)(yy & 0xffffu)), bo), 0.f);
            float z1 = fmaxf(fmaf(sa, bf2f((ushort)(yy >> 16)),     bo), 0.f);
            float wc0 = whL[ci][hh][0], wc1 = whL[ci][hh][1], wc2 = whL[ci][hh][2];
            a0[0] = fmaf(wc0, z0, a0[0]); a0[1] = fmaf(wc0, z1, a0[1]);
            a1[0] = fmaf(wc1, z0, a1[0]); a1[1] = fmaf(wc1, z1, a1[1]);
            a2[0] = fmaf(wc2, z0, a2[0]); a2[1] = fmaf(wc2, z1, a2[1]);
        }
    }
    const int vb = 2 * v2;
    atomicAdd(&T[(0 * 8 + b) * 512 + vb],     a0[0]);
    atomicAdd(&T[(0 * 8 + b) * 512 + vb + 1], a0[1]);
    atomicAdd(&T[(1 * 8 + b) * 512 + vb],     a1[0]);
    atomicAdd(&T[(1 * 8 + b) * 512 + vb + 1], a1[1]);
    atomicAdd(&T[(2 * 8 + b) * 512 + vb],     a2[0]);
    atomicAdd(&T[(2 * 8 + b) * 512 + vb + 1], a2[1]);
}

// r[b,w'] = sum_kw (valid u=w'+kw-1) interp_512->1024(T[kw][b])[u]
__global__ __launch_bounds__(256) void combine_r(const float* __restrict__ T,
                                                 float* __restrict__ r)
{
    int idx = blockIdx.x * 256 + threadIdx.x;   // 8192
    int b = idx >> 10, w = idx & 1023;
    const float scale = (float)(511.0 / 1023.0);
    float acc = 0.f;
    #pragma unroll
    for (int kw = 0; kw < 3; ++kw) {
        int u = w + kw - 1;
        if (u >= 0 && u < 1024) {
            float pos = (float)u * scale;
            int i0 = (int)pos;
            float f = pos - (float)i0;
            int i1 = min(i0 + 1, 511);
            const float* Tk = T + (size_t)(kw * 8 + b) * 512;
            float lo = Tk[i0];
            acc += fmaf(Tk[i1] - lo, f, lo);
        }
    }
    r[idx] = acc;
}

// out[b,w4] = sigmoid( up_{2048->4096}( up_{1024->2048}(r) ) )
__global__ __launch_bounds__(256) void final_kernel(const float* __restrict__ r,
                                                    float* __restrict__ out)
{
    int idx = blockIdx.x * 256 + threadIdx.x;   // 32768
    int b = idx >> 12, w4 = idx & 4095;
    const float s3 = (float)(2047.0 / 4095.0);
    const float s2 = (float)(1023.0 / 2047.0);
    const float* rb = r + b * 1024;

    float pos3 = (float)w4 * s3;
    int j0 = (int)pos3;
    float f3 = pos3 - (float)j0;
    int j1 = min(j0 + 1, 2047);

    float v[2];
    int jj[2] = {j0, j1};
    #pragma unroll
    for (int k = 0; k < 2; ++k) {
        float p = (float)jj[k] * s2;
        int i = (int)p;
        float f = p - (float)i;
        int i2 = min(i + 1, 1023);
        float lo = rb[i];
        v[k] = fmaf(rb[i2] - lo, f, lo);
    }
    float z = fmaf(v[1] - v[0], f3, v[0]);
    out[idx] = 1.0f / (1.0f + expf(-z));
}

extern "C" void kernel_launch(void* const* d_in, const int* in_sizes, int n_in,
                              void* d_out, int out_size, void* d_ws, size_t ws_size,
                              hipStream_t stream)
{
    const float* p2c   = (const float*)d_in[0];
    const float* wmsg  = (const float*)d_in[1];
    const float* gamma = (const float*)d_in[2];
    const float* beta  = (const float*)d_in[3];
    const float* wup2  = (const float*)d_in[4];
    const float* wc1   = (const float*)d_in[5];
    const float* wc2   = (const float*)d_in[6];
    float* out = (float*)d_out;
    float* ws  = (float*)d_ws;

    ushort* Xbf   = (ushort*)(ws + XBF_OFF);
    ushort* Ybf   = (ushort*)(ws + YBF_OFF);
    ushort* Mbf   = (ushort*)(ws + MBF_OFF);
    float*  coef1 = ws + COEF1_OFF;
    float*  coef2 = ws + COEF2_OFF;
    float*  wh    = ws + WH_OFF;
    float*  T     = ws + T_OFF;
    float*  st1   = ws + ST1_OFF;
    float*  st2   = ws + ST2_OFF;
    float*  r     = ws + R_OFF;

    hipMemsetAsync(T, 0, ZERO_FLOATS * sizeof(float), stream);  // T, st1, st2

    prep_mbf<<<256, 256, 0, stream>>>(wmsg, Mbf);
    prep_wh<<<768, 256, 0, stream>>>(wup2, wc1, wc2, wh);

    // scnn1: f32 input -> Xbf (bf16, logical order) + stats
    scnn_mfma<false><<<256, 512, 0, stream>>>(p2c, Mbf, Xbf, nullptr, st1);
    coef_kernel<<<1, 256, 0, stream>>>(st1, gamma, beta, coef1);

    // scnn2: reads relu(bn1(Xbf)) -> Ybf + stats
    scnn_mfma<true><<<256, 512, 0, stream>>>(Xbf, Mbf, Ybf, coef1, st2);
    coef_kernel<<<1, 256, 0, stream>>>(st2, gamma, beta, coef2);

    // folded conv + h-reduction, decomposed through the linear upsample
    conv_reduce<<<256, 256, 0, stream>>>(Ybf, coef2, wh, T);
    combine_r<<<32, 256, 0, stream>>>(T, r);

    // two upsamples + sigmoid
    final_kernel<<<128, 256, 0, stream>>>(r, out);
}